// Round 4
// baseline (574.312 us; speedup 1.0000x reference)
//
#include <hip/hip_runtime.h>
#include <math.h>

#define DDIM 16
#define NSTEPS 64
#define LUT_N 1024          // segments over [-8, 8]
#define LUT_SCALE 64.0f     // LUT_N / 16
#define LUT_BIAS 512.0f     // 8 * LUT_SCALE

typedef __fp16   fp16x2  __attribute__((ext_vector_type(2)));
typedef _Float16 half4   __attribute__((ext_vector_type(4)));
typedef float    floatx4 __attribute__((ext_vector_type(4)));

union pk2_to_h4 {
    fp16x2 p2[2];
    half4  h4;
};

// ---------------------------------------------------------------------------
// Pre-pack W^T / V^T into per-lane MFMA A-operand fragments (f16).
// V fragments are pre-scaled by 1/NSTEPS.
// ---------------------------------------------------------------------------
__global__ __launch_bounds__(256) void pack_wv(const float* __restrict__ W,
                                               const float* __restrict__ V,
                                               half4* __restrict__ pw,
                                               half4* __restrict__ pv)
{
    int t = blockIdx.x * 256 + threadIdx.x;   // 0..4095 = 64 steps * 64 lanes
    int L = t & 63;
    int s = t >> 6;
    int q = L >> 4, r = L & 15;
    const float inv_n = 1.0f / (float)NSTEPS;
    const float* Ws = W + s * DDIM * DDIM;
    const float* Vs = V + s * DDIM * DDIM;
    half4 w, v;
    #pragma unroll
    for (int j = 0; j < 4; ++j) {
        w[j] = (_Float16)Ws[(4 * q + j) * DDIM + r];
        v[j] = (_Float16)(Vs[(4 * q + j) * DDIM + r] * inv_n);
    }
    pw[t] = w;
    pv[t] = v;
}

// ---------------------------------------------------------------------------
// Piecewise-linear LUT for EXACT (erf) GELU over [-8, 8]; clamped-index
// extrapolation exact at both tails.
// ---------------------------------------------------------------------------
__global__ __launch_bounds__(256) void build_lut(float2* __restrict__ lut)
{
    int i = blockIdx.x * 256 + threadIdx.x;   // 0..1023
    const float h = 16.0f / (float)LUT_N;
    float x0 = -8.0f + i * h;
    float x1 = x0 + h;
    float g0 = 0.5f * x0 * (1.0f + erff(x0 * 0.70710678f));
    float g1 = 0.5f * x1 * (1.0f + erff(x1 * 0.70710678f));
    float a = (g1 - g0) * LUT_SCALE;
    float b = g0 - a * x0;
    lut[i] = make_float2(a, b);
}

// ---------------------------------------------------------------------------
// Main kernel. Per-tile GELU is split across the two independent pipes:
//   elems 0,1 -> LDS LUT gather   (LDS pipe, shared per-CU; was 104% busy at 4/4)
//   elems 2,3 -> A&S 7.1.25 erf   (VALU pipe; division-free except one v_rcp)
// Branch-free sign fold: g = 0.5*x + |x| * (0.5*erf(|x|/sqrt2)).
// ---------------------------------------------------------------------------
__global__ __launch_bounds__(256) void resnet_mfma_kernel(
    const float* __restrict__ x,
    const half4* __restrict__ pw,
    const half4* __restrict__ pv,
    const float2* __restrict__ lut_g,
    float* __restrict__ out)
{
    __shared__ float2 lut[LUT_N];   // 8 KB

    const int tid  = threadIdx.x;
    const int lane = tid & 63;
    const int wave = tid >> 6;
    const int q = lane >> 4, r = lane & 15;

    // Stage LUT into LDS: 512 float4 (= 1024 float2) / 256 threads = 2 each.
    {
        const float4* src = reinterpret_cast<const float4*>(lut_g);
        float4* dst = reinterpret_cast<float4*>(lut);
        dst[tid]       = src[tid];
        dst[tid + 256] = src[tid + 256];
    }

    const long rowbase = (long)blockIdx.x * 256 + (long)wave * 64;

    floatx4 h[4];
    #pragma unroll
    for (int t = 0; t < 4; ++t) {
        const float4* p = reinterpret_cast<const float4*>(
            x + (rowbase + t * 16 + r) * DDIM + 4 * q);
        float4 v = *p;
        h[t][0] = v.x; h[t][1] = v.y; h[t][2] = v.z; h[t][3] = v.w;
    }

    // A&S 7.1.25 constants (erf, |err| <= 5e-4 for arg >= 0)
    const float A1 = 0.278393f, A2 = 0.230389f, A3 = 0.000972f, A4 = 0.078108f;
    const float INV_SQRT2 = 0.70710678f;

    half4 wf = pw[lane];
    half4 vf = pv[lane];

    __syncthreads();   // LUT ready

    for (int s = 0; s < NSTEPS; ++s) {
        int sn = (s + 1) & (NSTEPS - 1);          // last iter wraps to 0 (unused)
        half4 wfn = pw[sn * 64 + lane];
        half4 vfn = pv[sn * 64 + lane];

        #pragma unroll
        for (int t = 0; t < 4; ++t) {
            pk2_to_h4 hc;
            hc.p2[0] = __builtin_amdgcn_cvt_pkrtz(h[t][0], h[t][1]);
            hc.p2[1] = __builtin_amdgcn_cvt_pkrtz(h[t][2], h[t][3]);

            floatx4 zero = {0.f, 0.f, 0.f, 0.f};
            floatx4 u = __builtin_amdgcn_mfma_f32_16x16x16f16(wf, hc.h4, zero, 0, 0, 0);

            // --- elems 0,1: LDS LUT gather (issue reads early) ---
            float x0 = u[0], x1 = u[1];
            float t0 = __builtin_amdgcn_fmed3f(fmaf(x0, LUT_SCALE, LUT_BIAS),
                                               0.0f, (float)(LUT_N - 1));
            float t1 = __builtin_amdgcn_fmed3f(fmaf(x1, LUT_SCALE, LUT_BIAS),
                                               0.0f, (float)(LUT_N - 1));
            float2 ab0 = lut[(unsigned)t0];
            float2 ab1 = lut[(unsigned)t1];

            // --- elems 2,3: A&S 7.1.25 polynomial erf (VALU only) ---
            float g2, g3;
            #pragma unroll
            for (int j = 2; j < 4; ++j) {
                float xv = u[j];
                float ax = fabsf(xv) * INV_SQRT2;
                float qd = fmaf(fmaf(fmaf(fmaf(A4, ax, A3), ax, A2), ax, A1), ax, 1.0f);
                float rr = __builtin_amdgcn_rcpf(qd);
                float r2 = rr * rr;
                float r4 = r2 * r2;
                float w  = fmaf(-0.5f, r4, 0.5f);     // 0.5*erf(|x|/sqrt2)
                float gg = fmaf(fabsf(xv), w, 0.5f * xv);
                if (j == 2) g2 = gg; else g3 = gg;
            }

            float g0v = fmaf(ab0.x, x0, ab0.y);
            float g1v = fmaf(ab1.x, x1, ab1.y);

            pk2_to_h4 gc;
            gc.p2[0] = __builtin_amdgcn_cvt_pkrtz(g0v, g1v);
            gc.p2[1] = __builtin_amdgcn_cvt_pkrtz(g2, g3);

            h[t] = __builtin_amdgcn_mfma_f32_16x16x16f16(vf, gc.h4, h[t], 0, 0, 0);
        }

        wf = wfn; vf = vfn;
    }

    #pragma unroll
    for (int t = 0; t < 4; ++t) {
        float4 v = make_float4(h[t][0], h[t][1], h[t][2], h[t][3]);
        *reinterpret_cast<float4*>(out + (rowbase + t * 16 + r) * DDIM + 4 * q) = v;
    }
}

extern "C" void kernel_launch(void* const* d_in, const int* in_sizes, int n_in,
                              void* d_out, int out_size, void* d_ws, size_t ws_size,
                              hipStream_t stream) {
    const float* x = (const float*)d_in[0];   // [B, 16] fp32
    const float* W = (const float*)d_in[1];   // [64, 16, 16] fp32
    const float* V = (const float*)d_in[2];   // [64, 16, 16] fp32
    float* out = (float*)d_out;

    half4* pw = (half4*)d_ws;                 // 64 steps * 64 lanes * 8B = 32KB
    half4* pv = pw + NSTEPS * 64;             // +32KB
    float2* lut = (float2*)(pv + NSTEPS * 64);// +8KB  (ws_size must be >= 72KB)

    pack_wv<<<16, 256, 0, stream>>>(W, V, pw, pv);
    build_lut<<<LUT_N / 256, 256, 0, stream>>>(lut);

    int batch = in_sizes[0] / DDIM;           // 2^21
    resnet_mfma_kernel<<<batch / 256, 256, 0, stream>>>(x, pw, pv, lut, out);
}

// Round 5
// 399.161 us; speedup vs baseline: 1.4388x; 1.4388x over previous
//
#include <hip/hip_runtime.h>
#include <math.h>

#define DDIM 16
#define NSTEPS 64

typedef __fp16   fp16x2  __attribute__((ext_vector_type(2)));
typedef _Float16 h2      __attribute__((ext_vector_type(2)));
typedef _Float16 half4   __attribute__((ext_vector_type(4)));
typedef float    floatx4 __attribute__((ext_vector_type(4)));

union pk_u      { fp16x2 fv; h2 hv; unsigned u; };
union h2x2_h4   { h2 g2[2]; half4 h4; };
union pk2_to_h4 { fp16x2 p2[2]; half4 h4; };
union us_h      { unsigned short u; _Float16 h; };

// ---------------------------------------------------------------------------
// Pre-pack W^T / V^T into per-lane MFMA A-operand fragments (f16).
// V fragments are pre-scaled by 1/NSTEPS.
// ---------------------------------------------------------------------------
__global__ __launch_bounds__(256) void pack_wv(const float* __restrict__ W,
                                               const float* __restrict__ V,
                                               half4* __restrict__ pw,
                                               half4* __restrict__ pv)
{
    int t = blockIdx.x * 256 + threadIdx.x;   // 0..4095 = 64 steps * 64 lanes
    int L = t & 63;
    int s = t >> 6;
    int q = L >> 4, r = L & 15;
    const float inv_n = 1.0f / (float)NSTEPS;
    const float* Ws = W + s * DDIM * DDIM;
    const float* Vs = V + s * DDIM * DDIM;
    half4 w, v;
    #pragma unroll
    for (int j = 0; j < 4; ++j) {
        w[j] = (_Float16)Ws[(4 * q + j) * DDIM + r];
        v[j] = (_Float16)(Vs[(4 * q + j) * DDIM + r] * inv_n);
    }
    pw[t] = w;
    pv[t] = v;
}

// ---------------------------------------------------------------------------
// GELU LUT indexed by the TOP 10 BITS of the f16 pattern of x
// (sign + 5 exp + 4 mantissa): 1024 log-spaced segments covering the whole
// f16 domain -> no clamping needed. Entry i: packed f16 (a,b), low16=a,
// with gelu(x) ~= a*x + b on the segment [bits(i<<6), bits((i+1)<<6)).
// Segments touching inf/nan encodings: g=x (positive) or g=0 (negative) —
// exact there. Max PWL error ~6e-4 (binade [1,2)), below f16 activation ulp.
// ---------------------------------------------------------------------------
__global__ __launch_bounds__(256) void build_lut16(unsigned* __restrict__ lut)
{
    int i = blockIdx.x * 256 + threadIdx.x;   // 0..1023
    int sign = i >> 9;
    int eo = (i >> 4) & 31;
    int en = ((i + 1) >> 4) & 31;
    float a, b;
    if (eo == 31 || en == 31) {               // segment touches inf/nan codes
        a = sign ? 0.0f : 1.0f;
        b = 0.0f;
    } else {
        us_h c0, c1;
        c0.u = (unsigned short)(i << 6);
        c1.u = (unsigned short)((i + 1) << 6);
        float x0 = (float)c0.h, x1 = (float)c1.h;
        float g0 = 0.5f * x0 * (1.0f + erff(x0 * 0.70710678f));
        float g1 = 0.5f * x1 * (1.0f + erff(x1 * 0.70710678f));
        a = (g1 - g0) / (x1 - x0);
        b = g0 - a * x0;
    }
    us_h ah, bh;
    ah.h = (_Float16)a;
    bh.h = (_Float16)b;
    lut[i] = ((unsigned)bh.u << 16) | (unsigned)ah.u;
}

// ---------------------------------------------------------------------------
// Main kernel (R2 structure). GELU per tile:
//   2x cvt_pkrtz (u->f16, needed for MFMA operand anyway)
//   4x (lshr+and) byte-offset from the f16 bits
//   4x ds_read_b32 gather (4KB LUT)
//   4x v_perm repack (a|b interleave -> a-pair / b-pair)
//   2x v_pk_fma_f16 -> result IS the f16 MFMA B-operand (no output pkrtz)
// ---------------------------------------------------------------------------
__global__ __launch_bounds__(256) void resnet_mfma_kernel(
    const float* __restrict__ x,
    const half4* __restrict__ pw,
    const half4* __restrict__ pv,
    const unsigned* __restrict__ lut_g,
    float* __restrict__ out)
{
    __shared__ unsigned lutw[1024];   // 4 KB

    const int tid  = threadIdx.x;
    const int lane = tid & 63;
    const int wave = tid >> 6;
    const int q = lane >> 4, r = lane & 15;

    // Stage LUT into LDS: 256 uint4 = 1024 u32, one per thread.
    {
        const uint4* src = reinterpret_cast<const uint4*>(lut_g);
        reinterpret_cast<uint4*>(lutw)[tid] = src[tid];
    }

    const long rowbase = (long)blockIdx.x * 256 + (long)wave * 64;

    floatx4 h[4];
    #pragma unroll
    for (int t = 0; t < 4; ++t) {
        const float4* p = reinterpret_cast<const float4*>(
            x + (rowbase + t * 16 + r) * DDIM + 4 * q);
        float4 v = *p;
        h[t][0] = v.x; h[t][1] = v.y; h[t][2] = v.z; h[t][3] = v.w;
    }

    half4 wf = pw[lane];
    half4 vf = pv[lane];

    __syncthreads();   // LUT ready

    const char* lb = reinterpret_cast<const char*>(lutw);

    for (int s = 0; s < NSTEPS; ++s) {
        int sn = (s + 1) & (NSTEPS - 1);          // last iter wraps to 0 (unused)
        half4 wfn = pw[sn * 64 + lane];
        half4 vfn = pv[sn * 64 + lane];

        #pragma unroll
        for (int t = 0; t < 4; ++t) {
            pk2_to_h4 hc;
            hc.p2[0] = __builtin_amdgcn_cvt_pkrtz(h[t][0], h[t][1]);
            hc.p2[1] = __builtin_amdgcn_cvt_pkrtz(h[t][2], h[t][3]);

            floatx4 zero = {0.f, 0.f, 0.f, 0.f};
            floatx4 u = __builtin_amdgcn_mfma_f32_16x16x16f16(wf, hc.h4, zero, 0, 0, 0);

            // u -> packed f16 (also the value fed to the PWL eval)
            pk_u p01, p23;
            p01.fv = __builtin_amdgcn_cvt_pkrtz(u[0], u[1]);
            p23.fv = __builtin_amdgcn_cvt_pkrtz(u[2], u[3]);

            // byte offsets = (f16 bits >> 6) * 4, straight from the packed words
            unsigned off0 = (p01.u >> 4) & 0xFFCu;
            unsigned off1 = (p01.u >> 20) & 0xFFCu;
            unsigned off2 = (p23.u >> 4) & 0xFFCu;
            unsigned off3 = (p23.u >> 20) & 0xFFCu;

            unsigned e0 = *reinterpret_cast<const unsigned*>(lb + off0);
            unsigned e1 = *reinterpret_cast<const unsigned*>(lb + off1);
            unsigned e2 = *reinterpret_cast<const unsigned*>(lb + off2);
            unsigned e3 = *reinterpret_cast<const unsigned*>(lb + off3);

            // repack (b|a)(b|a) -> (a1|a0), (b1|b0) ; then packed f16 fma
            pk_u a01, b01, a23, b23;
            a01.u = __builtin_amdgcn_perm(e1, e0, 0x05040100u);
            b01.u = __builtin_amdgcn_perm(e1, e0, 0x07060302u);
            a23.u = __builtin_amdgcn_perm(e3, e2, 0x05040100u);
            b23.u = __builtin_amdgcn_perm(e3, e2, 0x07060302u);

            h2x2_h4 gg;
            gg.g2[0] = a01.hv * p01.hv + b01.hv;   // v_pk_fma_f16
            gg.g2[1] = a23.hv * p23.hv + b23.hv;

            // h += gelu(u) @ (V/N)  (residual add folded into MFMA C operand)
            h[t] = __builtin_amdgcn_mfma_f32_16x16x16f16(vf, gg.h4, h[t], 0, 0, 0);
        }

        wf = wfn; vf = vfn;
    }

    #pragma unroll
    for (int t = 0; t < 4; ++t) {
        float4 v = make_float4(h[t][0], h[t][1], h[t][2], h[t][3]);
        *reinterpret_cast<float4*>(out + (rowbase + t * 16 + r) * DDIM + 4 * q) = v;
    }
}

extern "C" void kernel_launch(void* const* d_in, const int* in_sizes, int n_in,
                              void* d_out, int out_size, void* d_ws, size_t ws_size,
                              hipStream_t stream) {
    const float* x = (const float*)d_in[0];   // [B, 16] fp32
    const float* W = (const float*)d_in[1];   // [64, 16, 16] fp32
    const float* V = (const float*)d_in[2];   // [64, 16, 16] fp32
    float* out = (float*)d_out;

    half4* pw = (half4*)d_ws;                 // 64 steps * 64 lanes * 8B = 32KB
    half4* pv = pw + NSTEPS * 64;             // +32KB
    unsigned* lut = (unsigned*)(pv + NSTEPS * 64); // +4KB (ws_size >= 68KB)

    pack_wv<<<16, 256, 0, stream>>>(W, V, pw, pv);
    build_lut16<<<4, 256, 0, stream>>>(lut);

    int batch = in_sizes[0] / DDIM;           // 2^21
    resnet_mfma_kernel<<<batch / 256, 256, 0, stream>>>(x, pw, pv, lut, out);
}